// Round 9
// baseline (184.195 us; speedup 1.0000x reference)
//
#include <hip/hip_runtime.h>
#include <stdint.h>

#define B_ 64
#define K_ 8192
#define O_ 8192
#define R_ 64
#define NSTEP 32           // K steps of 256
#define BKI 256            // ints per row per step

typedef __attribute__((ext_vector_type(8))) short s16x8;      // 8 bf16
typedef __attribute__((ext_vector_type(4))) float f32x4;
typedef __attribute__((ext_vector_type(4))) int iv4;
typedef __attribute__((ext_vector_type(4))) uint32_t uv4;

// round-to-nearest-even f32 -> bf16, packed pair
__device__ __forceinline__ uint32_t rne_pack(float a, float b) {
  uint32_t ua = __float_as_uint(a), ub = __float_as_uint(b);
  ua += 0x7fffu + ((ua >> 16) & 1u);
  ub += 0x7fffu + ((ub >> 16) & 1u);
  return (ua >> 16) | (ub & 0xffff0000u);
}

// (w - 128) in [-128,127]: EXACT in bf16, truncation suffices
__device__ __forceinline__ uint32_t wpack(int w0, int w1) {
  float f0 = (float)(w0 - 128);
  float f1 = (float)(w1 - 128);
  return (__float_as_uint(f0) >> 16) | (__float_as_uint(f1) & 0xffff0000u);
}

__device__ __forceinline__ s16x8 afrag(uv4 x) {
  union { uv4 u; s16x8 v; } r; r.u = x; return r.v;
}

// ---------------------------------------------------------------------------
// ABLATION A: R6's exact W address pattern, zero consumption coupling.
// 512 blocks x 4 waves; wave w reads rows 4w..4w+3 of its block's 16-row
// band, 1 KB contiguous per load instruction, 32 sequential steps per row.
// ---------------------------------------------------------------------------
__global__ __launch_bounds__(256) void k_abl_row(
    const int* __restrict__ Wq, int* __restrict__ sink) {
  const int t = threadIdx.x;
  const int o0 = blockIdx.x * 16;
  const int w = t >> 6, lane = t & 63;
  const int* wr0 = Wq + (size_t)(o0 + 4 * w + 0) * K_ + lane * 4;
  const int* wr1 = Wq + (size_t)(o0 + 4 * w + 1) * K_ + lane * 4;
  const int* wr2 = Wq + (size_t)(o0 + 4 * w + 2) * K_ + lane * 4;
  const int* wr3 = Wq + (size_t)(o0 + 4 * w + 3) * K_ + lane * 4;
  iv4 a = {0, 0, 0, 0};
#pragma unroll 4
  for (int s = 0; s < NSTEP; ++s) {
    a ^= *(const iv4*)(wr0 + s * BKI);
    a ^= *(const iv4*)(wr1 + s * BKI);
    a ^= *(const iv4*)(wr2 + s * BKI);
    a ^= *(const iv4*)(wr3 + s * BKI);
  }
  sink[blockIdx.x * 256 + t] = a[0] ^ a[1] ^ a[2] ^ a[3];
}

// ---------------------------------------------------------------------------
// ABLATION B: pure address-order stream (copy-shaped upper bound).
// Block b reads the contiguous 512 KB slab [b*128Ki ints, ...).
// ---------------------------------------------------------------------------
__global__ __launch_bounds__(256) void k_abl_seq(
    const int* __restrict__ Wq, int* __restrict__ sink) {
  const int t = threadIdx.x;
  const int* base = Wq + (size_t)blockIdx.x * 131072 + t * 4;
  iv4 a = {0, 0, 0, 0};
#pragma unroll 4
  for (int i = 0; i < 128; ++i) a ^= *(const iv4*)(base + i * 1024);
  sink[blockIdx.x * 256 + t] = a[0] ^ a[1] ^ a[2] ^ a[3];
}

// ---------------------------------------------------------------------------
// k_prep: (a) all 256 blocks: pack x (fp32 [64][8192]) into MFMA-fragment-
//         major bf16 xf. (b) blocks 0..63: partial mid = x @ lora_A^T,
//         accumulated via fp32 atomicAdd (mid zeroed by memset).
// ---------------------------------------------------------------------------
__global__ __launch_bounds__(256) void k_prep(
    const float* __restrict__ x, const float* __restrict__ lora_A,
    uint16_t* __restrict__ xf, float* __restrict__ mid) {
  const int t = threadIdx.x;
  const int blk = blockIdx.x;

  {  // one fragment per thread: 65536 frags = 256 blocks x 256 threads
    const int gtid = blk * 256 + t;
    const int l = gtid & 63;
    const int m = (gtid >> 6) & 3;
    const int C = gtid >> 8;
    const int row = m * 16 + (l & 15);
    const int col = C * 32 + (l >> 4) * 8;
    const float* xp = x + (size_t)row * K_ + col;
    float4 v0 = *(const float4*)xp;
    float4 v1 = *(const float4*)(xp + 4);
    uint4 p;
    p.x = rne_pack(v0.x, v0.y);
    p.y = rne_pack(v0.z, v0.w);
    p.z = rne_pack(v1.x, v1.y);
    p.w = rne_pack(v1.z, v1.w);
    *(uint4*)(xf + (size_t)gtid * 8) = p;   // coalesced
  }

  if (blk >= 64) return;

  __shared__ float xs[64][133];
  __shared__ float as_[64][133];
  const int kr0 = blk * 128;
  const int row = t >> 2, seg = t & 3;
#pragma unroll
  for (int j = 0; j < 8; ++j) {
    const int c = seg * 32 + j * 4;
    float4 vx = *(const float4*)(x + (size_t)row * K_ + kr0 + c);
    float4 va = *(const float4*)(lora_A + (size_t)row * K_ + kr0 + c);
    xs[row][c] = vx.x; xs[row][c + 1] = vx.y; xs[row][c + 2] = vx.z; xs[row][c + 3] = vx.w;
    as_[row][c] = va.x; as_[row][c + 1] = va.y; as_[row][c + 2] = va.z; as_[row][c + 3] = va.w;
  }
  __syncthreads();

  const int bg = t >> 4, rg = t & 15;
  const int b0 = bg * 4, r0 = rg * 4;
  float acc[4][4];
#pragma unroll
  for (int i = 0; i < 4; ++i)
#pragma unroll
    for (int j = 0; j < 4; ++j) acc[i][j] = 0.f;

  for (int k = 0; k < 128; ++k) {
    float xv[4], av[4];
#pragma unroll
    for (int i = 0; i < 4; ++i) xv[i] = xs[b0 + i][k];
#pragma unroll
    for (int j = 0; j < 4; ++j) av[j] = as_[r0 + j][k];
#pragma unroll
    for (int i = 0; i < 4; ++i)
#pragma unroll
      for (int j = 0; j < 4; ++j) acc[i][j] += xv[i] * av[j];
  }

#pragma unroll
  for (int i = 0; i < 4; ++i)
#pragma unroll
    for (int j = 0; j < 4; ++j)
      atomicAdd(&mid[(b0 + i) * R_ + (r0 + j)], acc[i][j]);
}

// ---------------------------------------------------------------------------
// k_main: unchanged from R7 (92.4 us baseline).
// ---------------------------------------------------------------------------
__global__ __launch_bounds__(256, 2) void k_main(
    const int* __restrict__ Wq, const uint16_t* __restrict__ xf,
    const float* __restrict__ scale, const float* __restrict__ lora_B,
    const float* __restrict__ bias, const float* __restrict__ mid,
    float* __restrict__ out) {
  __shared__ uint16_t wbs[2][16][264];
  __shared__ uint16_t midb[64][72];
  __shared__ uint16_t lob[16][72];

  const int t = threadIdx.x;
  const int o0 = blockIdx.x * 16;
  const int w = t >> 6, lane = t & 63, il = lane & 15, g = lane >> 4;
  const int m0 = w * 16;

  const int* wr0 = Wq + (size_t)(o0 + 4 * w + 0) * K_ + lane * 4;
  const int* wr1 = Wq + (size_t)(o0 + 4 * w + 1) * K_ + lane * 4;
  const int* wr2 = Wq + (size_t)(o0 + 4 * w + 2) * K_ + lane * 4;
  const int* wr3 = Wq + (size_t)(o0 + 4 * w + 3) * K_ + lane * 4;

  const uint16_t* xbase = xf + ((size_t)w * 64 + lane) * 8;

  iv4 rA0, rA1, rA2, rA3, rB0, rB1, rB2, rB3;

#define LOADW(P, S)                                                        \
  do {                                                                     \
    r##P##0 = __builtin_nontemporal_load((const iv4*)(wr0 + (S) * BKI));   \
    r##P##1 = __builtin_nontemporal_load((const iv4*)(wr1 + (S) * BKI));   \
    r##P##2 = __builtin_nontemporal_load((const iv4*)(wr2 + (S) * BKI));   \
    r##P##3 = __builtin_nontemporal_load((const iv4*)(wr3 + (S) * BKI));   \
  } while (0)

  LOADW(A, 0);
  LOADW(B, 1);

  {  // prologue: stage midb + lob
    const int row = t >> 2;
    const int r0 = (t & 3) * 16;
    const float* mp = mid + row * R_ + r0;
    float4 a0 = *(const float4*)(mp);
    float4 a1 = *(const float4*)(mp + 4);
    float4 a2 = *(const float4*)(mp + 8);
    float4 a3 = *(const float4*)(mp + 12);
    uint4 p0, p1;
    p0.x = rne_pack(a0.x, a0.y); p0.y = rne_pack(a0.z, a0.w);
    p0.z = rne_pack(a1.x, a1.y); p0.w = rne_pack(a1.z, a1.w);
    p1.x = rne_pack(a2.x, a2.y); p1.y = rne_pack(a2.z, a2.w);
    p1.z = rne_pack(a3.x, a3.y); p1.w = rne_pack(a3.z, a3.w);
    *(uint4*)&midb[row][r0] = p0;
    *(uint4*)&midb[row][r0 + 8] = p1;
    if (t < 64) {
      const int row2 = t >> 2;
      const float* lp = lora_B + (size_t)(o0 + row2) * R_ + r0;
      float4 c0 = *(const float4*)(lp);
      float4 c1 = *(const float4*)(lp + 4);
      float4 c2 = *(const float4*)(lp + 8);
      float4 c3 = *(const float4*)(lp + 12);
      uint4 q0, q1;
      q0.x = rne_pack(c0.x, c0.y); q0.y = rne_pack(c0.z, c0.w);
      q0.z = rne_pack(c1.x, c1.y); q0.w = rne_pack(c1.z, c1.w);
      q1.x = rne_pack(c2.x, c2.y); q1.y = rne_pack(c2.z, c2.w);
      q1.z = rne_pack(c3.x, c3.y); q1.w = rne_pack(c3.z, c3.w);
      *(uint4*)&lob[row2][r0] = q0;
      *(uint4*)&lob[row2][r0 + 8] = q1;
    }
  }
  __syncthreads();

  f32x4 acc2 = {0.f, 0.f, 0.f, 0.f};
#pragma unroll
  for (int kf = 0; kf < 2; ++kf) {
    s16x8 am = *(const s16x8*)&midb[m0 + il][kf * 32 + g * 8];
    s16x8 bl = *(const s16x8*)&lob[il][kf * 32 + g * 8];
    acc2 = __builtin_amdgcn_mfma_f32_16x16x32_bf16(am, bl, acc2, 0, 0, 0);
  }

  const float sc = scale[o0 + il];
  const float bi = bias[o0 + il];

  f32x4 acc = {0.f, 0.f, 0.f, 0.f};

#define STEP(P, BUF, S)                                                        \
  do {                                                                         \
    uint2 u0, u1, u2, u3;                                                      \
    u0.x = wpack(r##P##0[0], r##P##0[1]); u0.y = wpack(r##P##0[2], r##P##0[3]);\
    u1.x = wpack(r##P##1[0], r##P##1[1]); u1.y = wpack(r##P##1[2], r##P##1[3]);\
    u2.x = wpack(r##P##2[0], r##P##2[1]); u2.y = wpack(r##P##2[2], r##P##2[3]);\
    u3.x = wpack(r##P##3[0], r##P##3[1]); u3.y = wpack(r##P##3[2], r##P##3[3]);\
    *(uint2*)&wbs[BUF][4 * w + 0][lane * 4] = u0;                              \
    *(uint2*)&wbs[BUF][4 * w + 1][lane * 4] = u1;                              \
    *(uint2*)&wbs[BUF][4 * w + 2][lane * 4] = u2;                              \
    *(uint2*)&wbs[BUF][4 * w + 3][lane * 4] = u3;                              \
    __syncthreads();                                                           \
    if ((S) + 2 < NSTEP) LOADW(P, (S) + 2);                                    \
    uv4 xq0 = *(const uv4*)(xbase + ((size_t)((S) * 8 + 0)) * 2048);           \
    uv4 xq1 = *(const uv4*)(xbase + ((size_t)((S) * 8 + 1)) * 2048);           \
    uv4 xq2 = *(const uv4*)(xbase + ((size_t)((S) * 8 + 2)) * 2048);           \
    uv4 xq3 = *(const uv4*)(xbase + ((size_t)((S) * 8 + 3)) * 2048);           \
    uv4 xq4 = *(const uv4*)(xbase + ((size_t)((S) * 8 + 4)) * 2048);           \
    uv4 xq5 = *(const uv4*)(xbase + ((size_t)((S) * 8 + 5)) * 2048);           \
    uv4 xq6 = *(const uv4*)(xbase + ((size_t)((S) * 8 + 6)) * 2048);           \
    uv4 xq7 = *(const uv4*)(xbase + ((size_t)((S) * 8 + 7)) * 2048);           \
    s16x8 b0 = *(const s16x8*)&wbs[BUF][il][0 * 32 + g * 8];                   \
    acc = __builtin_amdgcn_mfma_f32_16x16x32_bf16(afrag(xq0), b0, acc, 0, 0, 0); \
    s16x8 b1 = *(const s16x8*)&wbs[BUF][il][1 * 32 + g * 8];                   \
    acc = __builtin_amdgcn_mfma_f32_16x16x32_bf16(afrag(xq1), b1, acc, 0, 0, 0); \
    s16x8 b2 = *(const s16x8*)&wbs[BUF][il][2 * 32 + g * 8];                   \
    acc = __builtin_amdgcn_mfma_f32_16x16x32_bf16(afrag(xq2), b2, acc, 0, 0, 0); \
    s16x8 b3 = *(const s16x8*)&wbs[BUF][il][3 * 32 + g * 8];                   \
    acc = __builtin_amdgcn_mfma_f32_16x16x32_bf16(afrag(xq3), b3, acc, 0, 0, 0); \
    s16x8 b4 = *(const s16x8*)&wbs[BUF][il][4 * 32 + g * 8];                   \
    acc = __builtin_amdgcn_mfma_f32_16x16x32_bf16(afrag(xq4), b4, acc, 0, 0, 0); \
    s16x8 b5 = *(const s16x8*)&wbs[BUF][il][5 * 32 + g * 8];                   \
    acc = __builtin_amdgcn_mfma_f32_16x16x32_bf16(afrag(xq5), b5, acc, 0, 0, 0); \
    s16x8 b6 = *(const s16x8*)&wbs[BUF][il][6 * 32 + g * 8];                   \
    acc = __builtin_amdgcn_mfma_f32_16x16x32_bf16(afrag(xq6), b6, acc, 0, 0, 0); \
    s16x8 b7 = *(const s16x8*)&wbs[BUF][il][7 * 32 + g * 8];                   \
    acc = __builtin_amdgcn_mfma_f32_16x16x32_bf16(afrag(xq7), b7, acc, 0, 0, 0); \
  } while (0)

  for (int s = 0; s < NSTEP; s += 2) {
    STEP(A, 0, s);
    STEP(B, 1, s + 1);
  }
#undef LOADW
#undef STEP

#pragma unroll
  for (int j = 0; j < 4; ++j) {
    const int b = m0 + g * 4 + j;
    out[(size_t)b * O_ + o0 + il] = sc * acc[j] + bi + 0.25f * acc2[j];
  }
}

// ---------------------------------------------------------------------------
extern "C" void kernel_launch(void* const* d_in, const int* in_sizes, int n_in,
                              void* d_out, int out_size, void* d_ws, size_t ws_size,
                              hipStream_t stream) {
  const float* x = (const float*)d_in[0];
  const int* Wq = (const int*)d_in[1];
  const float* scale = (const float*)d_in[2];
  const float* lora_A = (const float*)d_in[3];
  const float* lora_B = (const float*)d_in[4];
  const float* bias = (const float*)d_in[5];
  float* out = (float*)d_out;

  uint16_t* xf = (uint16_t*)d_ws;                     // 1 MiB frag-major x
  float* mid = (float*)((char*)d_ws + (2u << 20));    // 16 KiB fp32
  int* sink = (int*)((char*)d_ws + (40u << 20));      // 512 KiB ablation sink

  // --- diagnostic ablations (this round only): measure W-stream rate ---
  k_abl_row<<<O_ / 16, 256, 0, stream>>>(Wq, sink);
  k_abl_seq<<<O_ / 16, 256, 0, stream>>>(Wq, sink);

  hipMemsetAsync(mid, 0, B_ * R_ * sizeof(float), stream);
  k_prep<<<256, 256, 0, stream>>>(x, lora_A, xf, mid);
  k_main<<<O_ / 16, 256, 0, stream>>>(Wq, xf, scale, lora_B, bias, mid, out);
}

// Round 10
// 97.087 us; speedup vs baseline: 1.8972x; 1.8972x over previous
//
#include <hip/hip_runtime.h>
#include <stdint.h>

#define B_ 64
#define K_ 8192
#define O_ 8192
#define R_ 64
#define NC 128          // out-cols per block
#define KS 8            // K-split ways
#define KSL (K_ / KS)   // 1024
#define BK 64           // ints of K per step
#define NST (KSL / BK)  // 16 steps

typedef __attribute__((ext_vector_type(8))) short s16x8;      // 8 bf16
typedef __attribute__((ext_vector_type(4))) float f32x4;
typedef __attribute__((ext_vector_type(4))) int iv4;

// round-to-nearest-even f32 -> bf16, packed pair
__device__ __forceinline__ uint32_t rne_pack(float a, float b) {
  uint32_t ua = __float_as_uint(a), ub = __float_as_uint(b);
  ua += 0x7fffu + ((ua >> 16) & 1u);
  ub += 0x7fffu + ((ub >> 16) & 1u);
  return (ua >> 16) | (ub & 0xffff0000u);
}

// (w - 128) in [-128,127]: EXACT in bf16, truncation suffices
__device__ __forceinline__ uint32_t wpack(int w0, int w1) {
  float f0 = (float)(w0 - 128);
  float f1 = (float)(w1 - 128);
  return (__float_as_uint(f0) >> 16) | (__float_as_uint(f1) & 0xffff0000u);
}

// ---------------------------------------------------------------------------
// k_prep: (a) x (fp32 [64][8192]) -> bf16 xbg row-major (all 256 blocks)
//         (b) blocks 0..63: partial mid = x @ lora_A^T over a 128-wide K slab,
//             accumulated via fp32 atomicAdd (mid zeroed by memset).
// ---------------------------------------------------------------------------
__global__ __launch_bounds__(256) void k_prep(
    const float* __restrict__ x, const float* __restrict__ lora_A,
    uint16_t* __restrict__ xbg, float* __restrict__ mid) {
  const int t = threadIdx.x;
  const int blk = blockIdx.x;

  {  // x -> bf16, 2048 elems per block, 8 per thread
    const size_t base = (size_t)blk * 2048 + (size_t)t * 8;
    float4 v0 = *(const float4*)(x + base);
    float4 v1 = *(const float4*)(x + base + 4);
    uint4 p;
    p.x = rne_pack(v0.x, v0.y);
    p.y = rne_pack(v0.z, v0.w);
    p.z = rne_pack(v1.x, v1.y);
    p.w = rne_pack(v1.z, v1.w);
    *(uint4*)(xbg + base) = p;
  }

  if (blk >= 64) return;

  __shared__ float xs[64][133];
  __shared__ float as_[64][133];
  const int kr0 = blk * 128;
  const int row = t >> 2, seg = t & 3;
#pragma unroll
  for (int j = 0; j < 8; ++j) {
    const int c = seg * 32 + j * 4;
    float4 vx = *(const float4*)(x + (size_t)row * K_ + kr0 + c);
    float4 va = *(const float4*)(lora_A + (size_t)row * K_ + kr0 + c);
    xs[row][c] = vx.x; xs[row][c + 1] = vx.y; xs[row][c + 2] = vx.z; xs[row][c + 3] = vx.w;
    as_[row][c] = va.x; as_[row][c + 1] = va.y; as_[row][c + 2] = va.z; as_[row][c + 3] = va.w;
  }
  __syncthreads();

  const int bg = t >> 4, rg = t & 15;
  const int b0 = bg * 4, r0 = rg * 4;
  float acc[4][4];
#pragma unroll
  for (int i = 0; i < 4; ++i)
#pragma unroll
    for (int j = 0; j < 4; ++j) acc[i][j] = 0.f;

  for (int k = 0; k < 128; ++k) {
    float xv[4], av[4];
#pragma unroll
    for (int i = 0; i < 4; ++i) xv[i] = xs[b0 + i][k];
#pragma unroll
    for (int j = 0; j < 4; ++j) av[j] = as_[r0 + j][k];
#pragma unroll
    for (int i = 0; i < 4; ++i)
#pragma unroll
      for (int j = 0; j < 4; ++j) acc[i][j] += xv[i] * av[j];
  }

#pragma unroll
  for (int i = 0; i < 4; ++i)
#pragma unroll
    for (int j = 0; j < 4; ++j)
      atomicAdd(&mid[(b0 + i) * R_ + (r0 + j)], acc[i][j]);
}

// ---------------------------------------------------------------------------
// k_main: 512 blocks = (cg 0..63) x (ksb 0..7). Block = 128 out-cols x 64
// batch x K=1024. 8 waves: wave w -> col-half (w&1)*64, batch-group (w>>1)*16.
// Per step (64 ints of K): stage W 128x64 (wave w stages rows w*16..+15,
// 1 KB/instr in 4-row chunks, nontemporal) and x 64x64 (1 instr/thread, L2)
// into LDS stride-74 bf16 (odd-dword: <=2-way banks for b128 frag reads).
// Reg-dbuf cadence, one __syncthreads per step. x read ONCE per block:
// aggregate x traffic 64 MB (was 512 MB). Partials -> part[ksb][64][8192].
// ---------------------------------------------------------------------------
__global__ __launch_bounds__(512, 4) void k_main(
    const int* __restrict__ Wq, const uint16_t* __restrict__ xbg,
    float* __restrict__ part) {
  __shared__ uint16_t wls[2][NC][74];   // ~37.9 KB
  __shared__ uint16_t xls[2][B_][74];   // ~18.9 KB

  const int t = threadIdx.x;
  const int w = t >> 6, lane = t & 63, il = lane & 15, g = lane >> 4;
  const int cg = blockIdx.x >> 3;     // 0..63
  const int ksb = blockIdx.x & 7;     // 0..7
  const int o0b = cg * NC;
  const int kb = ksb * KSL;

  // W staging coords: wave w stages rows w*16 .. w*16+15, 4 instrs x 4 rows
  const int wr = lane >> 4;           // sub-row 0..3 within instr
  const int wc = (lane & 15) * 4;     // int col 0..60 within the 64-int step
  const int* wp0 = Wq + (size_t)(o0b + w * 16 + 0 + wr) * K_ + kb + wc;
  const int* wp1 = Wq + (size_t)(o0b + w * 16 + 4 + wr) * K_ + kb + wc;
  const int* wp2 = Wq + (size_t)(o0b + w * 16 + 8 + wr) * K_ + kb + wc;
  const int* wp3 = Wq + (size_t)(o0b + w * 16 + 12 + wr) * K_ + kb + wc;

  // x staging coords: thread -> one 16B chunk per step
  const int xrow = t >> 3, xco = (t & 7) * 8;
  const uint16_t* xp = xbg + (size_t)xrow * K_ + kb + xco;

  // fragment read coords
  const int mrow = (w >> 1) * 16 + il;       // A: batch row
  const int nb = (w & 1) * 64;               // B: col base

  iv4 wA0, wA1, wA2, wA3, wB0, wB1, wB2, wB3;
  uint4 xA, xB;

#define LOADW(P, S)                                                          \
  do {                                                                       \
    w##P##0 = __builtin_nontemporal_load((const iv4*)(wp0 + (S) * BK));      \
    w##P##1 = __builtin_nontemporal_load((const iv4*)(wp1 + (S) * BK));      \
    w##P##2 = __builtin_nontemporal_load((const iv4*)(wp2 + (S) * BK));      \
    w##P##3 = __builtin_nontemporal_load((const iv4*)(wp3 + (S) * BK));      \
  } while (0)
#define LOADX(P, S) x##P = *(const uint4*)(xp + (S) * BK)

  // prologue: 2 banks in flight
  LOADW(A, 0); LOADX(A, 0);
  LOADW(B, 1); LOADX(B, 1);

  f32x4 ac0 = {0.f,0.f,0.f,0.f}, ac1 = {0.f,0.f,0.f,0.f};
  f32x4 ac2 = {0.f,0.f,0.f,0.f}, ac3 = {0.f,0.f,0.f,0.f};

#define STEP(P, BUF, S)                                                        \
  do {                                                                         \
    uint2 u;                                                                   \
    u.x = wpack(w##P##0[0], w##P##0[1]); u.y = wpack(w##P##0[2], w##P##0[3]);  \
    *(uint2*)&wls[BUF][w * 16 + 0 + wr][wc] = u;                               \
    u.x = wpack(w##P##1[0], w##P##1[1]); u.y = wpack(w##P##1[2], w##P##1[3]);  \
    *(uint2*)&wls[BUF][w * 16 + 4 + wr][wc] = u;                               \
    u.x = wpack(w##P##2[0], w##P##2[1]); u.y = wpack(w##P##2[2], w##P##2[3]);  \
    *(uint2*)&wls[BUF][w * 16 + 8 + wr][wc] = u;                               \
    u.x = wpack(w##P##3[0], w##P##3[1]); u.y = wpack(w##P##3[2], w##P##3[3]);  \
    *(uint2*)&wls[BUF][w * 16 + 12 + wr][wc] = u;                              \
    *(uint4*)&xls[BUF][xrow][xco] = x##P;                                      \
    __syncthreads();                                                           \
    if ((S) + 2 < NST) { LOADW(P, (S) + 2); LOADX(P, (S) + 2); }               \
    s16x8 af0 = *(const s16x8*)&xls[BUF][mrow][0 * 32 + g * 8];                \
    s16x8 bf0 = *(const s16x8*)&wls[BUF][nb + 0 * 16 + il][0 * 32 + g * 8];    \
    ac0 = __builtin_amdgcn_mfma_f32_16x16x32_bf16(af0, bf0, ac0, 0, 0, 0);     \
    s16x8 bf1 = *(const s16x8*)&wls[BUF][nb + 1 * 16 + il][0 * 32 + g * 8];    \
    ac1 = __builtin_amdgcn_mfma_f32_16x16x32_bf16(af0, bf1, ac1, 0, 0, 0);     \
    s16x8 bf2 = *(const s16x8*)&wls[BUF][nb + 2 * 16 + il][0 * 32 + g * 8];    \
    ac2 = __builtin_amdgcn_mfma_f32_16x16x32_bf16(af0, bf2, ac2, 0, 0, 0);     \
    s16x8 bf3 = *(const s16x8*)&wls[BUF][nb + 3 * 16 + il][0 * 32 + g * 8];    \
    ac3 = __builtin_amdgcn_mfma_f32_16x16x32_bf16(af0, bf3, ac3, 0, 0, 0);     \
    s16x8 af1 = *(const s16x8*)&xls[BUF][mrow][1 * 32 + g * 8];                \
    s16x8 bg0 = *(const s16x8*)&wls[BUF][nb + 0 * 16 + il][1 * 32 + g * 8];    \
    ac0 = __builtin_amdgcn_mfma_f32_16x16x32_bf16(af1, bg0, ac0, 0, 0, 0);     \
    s16x8 bg1 = *(const s16x8*)&wls[BUF][nb + 1 * 16 + il][1 * 32 + g * 8];    \
    ac1 = __builtin_amdgcn_mfma_f32_16x16x32_bf16(af1, bg1, ac1, 0, 0, 0);     \
    s16x8 bg2 = *(const s16x8*)&wls[BUF][nb + 2 * 16 + il][1 * 32 + g * 8];    \
    ac2 = __builtin_amdgcn_mfma_f32_16x16x32_bf16(af1, bg2, ac2, 0, 0, 0);     \
    s16x8 bg3 = *(const s16x8*)&wls[BUF][nb + 3 * 16 + il][1 * 32 + g * 8];    \
    ac3 = __builtin_amdgcn_mfma_f32_16x16x32_bf16(af1, bg3, ac3, 0, 0, 0);     \
  } while (0)

  for (int s = 0; s < NST; s += 2) {
    STEP(A, 0, s);
    STEP(B, 1, s + 1);
  }
#undef LOADW
#undef LOADX
#undef STEP

  // ---- partial store: C/D col=il (out col), row=g*4+jj (batch) ----
  float* pp = part + (size_t)ksb * (B_ * O_);
#pragma unroll
  for (int jj = 0; jj < 4; ++jj) {
    const int b = (w >> 1) * 16 + g * 4 + jj;
    float* row = pp + (size_t)b * O_ + o0b + nb + il;
    row[0]  = ac0[jj];
    row[16] = ac1[jj];
    row[32] = ac2[jj];
    row[48] = ac3[jj];
  }
}

// ---------------------------------------------------------------------------
// k_fin: out = scale * (sum of 8 partials) + bias + 0.25 * (mid @ lora_B^T).
// ---------------------------------------------------------------------------
__global__ __launch_bounds__(256) void k_fin(
    const float* __restrict__ part, const float* __restrict__ scale,
    const float* __restrict__ lora_B, const float* __restrict__ bias,
    const float* __restrict__ mid, float* __restrict__ out) {
  __shared__ uint16_t midb[64][72];
  __shared__ uint16_t lob[16][72];

  const int t = threadIdx.x;
  const int o0 = blockIdx.x * 16;
  const int wave = t >> 6;
  const int lane = t & 63;
  const int il = lane & 15;
  const int g = lane >> 4;
  const int m0 = wave * 16;

  {  // stage mid (all threads) + lora_B tile (threads 0..63) as bf16
    const int row = t >> 2;
    const int r0 = (t & 3) * 16;
    const float* mp = mid + row * R_ + r0;
    float4 a0 = *(const float4*)(mp);
    float4 a1 = *(const float4*)(mp + 4);
    float4 a2 = *(const float4*)(mp + 8);
    float4 a3 = *(const float4*)(mp + 12);
    uint4 p0, p1;
    p0.x = rne_pack(a0.x, a0.y); p0.y = rne_pack(a0.z, a0.w);
    p0.z = rne_pack(a1.x, a1.y); p0.w = rne_pack(a1.z, a1.w);
    p1.x = rne_pack(a2.x, a2.y); p1.y = rne_pack(a2.z, a2.w);
    p1.z = rne_pack(a3.x, a3.y); p1.w = rne_pack(a3.z, a3.w);
    *(uint4*)&midb[row][r0] = p0;
    *(uint4*)&midb[row][r0 + 8] = p1;
    if (t < 64) {
      const int row2 = t >> 2;
      const float* lp = lora_B + (size_t)(o0 + row2) * R_ + r0;
      float4 c0 = *(const float4*)(lp);
      float4 c1 = *(const float4*)(lp + 4);
      float4 c2 = *(const float4*)(lp + 8);
      float4 c3 = *(const float4*)(lp + 12);
      uint4 q0, q1;
      q0.x = rne_pack(c0.x, c0.y); q0.y = rne_pack(c0.z, c0.w);
      q0.z = rne_pack(c1.x, c1.y); q0.w = rne_pack(c1.z, c1.w);
      q1.x = rne_pack(c2.x, c2.y); q1.y = rne_pack(c2.z, c2.w);
      q1.z = rne_pack(c3.x, c3.y); q1.w = rne_pack(c3.z, c3.w);
      *(uint4*)&lob[row2][r0] = q0;
      *(uint4*)&lob[row2][r0 + 8] = q1;
    }
  }
  __syncthreads();

  f32x4 acc2 = {0.f, 0.f, 0.f, 0.f};
#pragma unroll
  for (int kf = 0; kf < 2; ++kf) {
    s16x8 am = *(const s16x8*)&midb[m0 + il][kf * 32 + g * 8];
    s16x8 bl = *(const s16x8*)&lob[il][kf * 32 + g * 8];
    acc2 = __builtin_amdgcn_mfma_f32_16x16x32_bf16(am, bl, acc2, 0, 0, 0);
  }

  const float sc = scale[o0 + il];
  const float bi = bias[o0 + il];

#pragma unroll
  for (int j = 0; j < 4; ++j) {
    const int b = m0 + g * 4 + j;
    const size_t idx = (size_t)b * O_ + o0 + il;
    float s = 0.f;
#pragma unroll
    for (int k = 0; k < KS; ++k) s += part[(size_t)k * (B_ * O_) + idx];
    out[idx] = sc * s + bi + 0.25f * acc2[j];
  }
}

// ---------------------------------------------------------------------------
extern "C" void kernel_launch(void* const* d_in, const int* in_sizes, int n_in,
                              void* d_out, int out_size, void* d_ws, size_t ws_size,
                              hipStream_t stream) {
  const float* x = (const float*)d_in[0];
  const int* Wq = (const int*)d_in[1];
  const float* scale = (const float*)d_in[2];
  const float* lora_A = (const float*)d_in[3];
  const float* lora_B = (const float*)d_in[4];
  const float* bias = (const float*)d_in[5];
  float* out = (float*)d_out;

  uint16_t* xbg = (uint16_t*)d_ws;                    // 1 MiB bf16 x, row-major
  float* mid = (float*)((char*)d_ws + (2u << 20));    // 16 KiB fp32
  float* part = (float*)((char*)d_ws + (4u << 20));   // 16 MiB fp32 (8 x 2 MiB)

  hipMemsetAsync(mid, 0, B_ * R_ * sizeof(float), stream);
  k_prep<<<256, 256, 0, stream>>>(x, lora_A, xbg, mid);
  k_main<<<KS * (O_ / NC), 512, 0, stream>>>(Wq, xbg, part);
  k_fin<<<O_ / 16, 256, 0, stream>>>(part, scale, lora_B, bias, mid, out);
}